// Round 5
// baseline (382.408 us; speedup 1.0000x reference)
//
#include <hip/hip_runtime.h>

#define NN 100000
#define NE 1250000
#define CAP 64   // ELL capacity; deg ~ Poisson(12.5), P(deg>64) ~ 0

typedef unsigned short u16;

__device__ inline float b2f(u16 h) { return __uint_as_float(((unsigned int)h) << 16); }
__device__ inline u16 f2b(float f) {
    unsigned int u = __float_as_uint(f);
    u = (u + 0x7FFFu + ((u >> 16) & 1u)) >> 16;   // RNE
    return (u16)u;
}

// ---------------- ELL build: degree count + neighbor-list fill ----------------
__global__ void build_ell(const int* __restrict__ src, const int* __restrict__ dst,
                          int* __restrict__ cnt, int* __restrict__ ell) {
    int e4 = blockIdx.x * blockDim.x + threadIdx.x;   // over NE/4
    if (e4 >= NE / 4) return;
    int4 s = ((const int4*)src)[e4];
    int4 d = ((const int4*)dst)[e4];
    int slot;
    slot = atomicAdd(&cnt[d.x], 1); if (slot < CAP) ell[(size_t)d.x * CAP + slot] = s.x;
    slot = atomicAdd(&cnt[d.y], 1); if (slot < CAP) ell[(size_t)d.y * CAP + slot] = s.y;
    slot = atomicAdd(&cnt[d.z], 1); if (slot < CAP) ell[(size_t)d.z * CAP + slot] = s.z;
    slot = atomicAdd(&cnt[d.w], 1); if (slot < CAP) ell[(size_t)d.w * CAP + slot] = s.w;
}

// ---------------- xform1: y1h = bf16(x@w1l), s1h = bf16(x@w1r + b1) ----------------
// wave = 8 nodes; x rows in registers; per-k: 2 LDS weight reads + 8 shfl + 16 FMA
__global__ void __launch_bounds__(512) xform1(
        const float* __restrict__ x,
        const float* __restrict__ w1l, const float* __restrict__ b1,
        const float* __restrict__ w1r,
        u16* __restrict__ y1h, u16* __restrict__ s1h) {
    __shared__ float lwl[64 * 64];
    __shared__ float lwr[64 * 64];
    __shared__ float lb[64];
    for (int i = threadIdx.x; i < 64 * 64; i += 512) { lwl[i] = w1l[i]; lwr[i] = w1r[i]; }
    if (threadIdx.x < 64) lb[threadIdx.x] = b1[threadIdx.x];
    __syncthreads();

    int w    = threadIdx.x >> 6;
    int lane = threadIdx.x & 63;
    int n0   = (blockIdx.x * 8 + w) * 8;   // 8 nodes per wave
    if (n0 >= NN) return;                  // NN % 8 == 0 -> full 8 when valid

    float xr[8];
#pragma unroll
    for (int r = 0; r < 8; ++r) xr[r] = x[(size_t)(n0 + r) * 64 + lane];

    float accy[8], accs[8];
    float bias = lb[lane];
#pragma unroll
    for (int r = 0; r < 8; ++r) { accy[r] = 0.0f; accs[r] = bias; }

#pragma unroll
    for (int k = 0; k < 64; ++k) {
        float wl = lwl[k * 64 + lane];
        float wr = lwr[k * 64 + lane];
#pragma unroll
        for (int r = 0; r < 8; ++r) {
            float xv = __shfl(xr[r], k);
            accy[r] += xv * wl;
            accs[r] += xv * wr;
        }
    }

#pragma unroll
    for (int r = 0; r < 8; ++r) {
        y1h[(size_t)(n0 + r) * 64 + lane] = f2b(accy[r]);
        s1h[(size_t)(n0 + r) * 64 + lane] = f2b(accs[r]);
    }
}

// ---------------- gather1: h1h = bf16(relu(mean(y1h) + s1h))  [in-place over s1h] ----
__global__ void __launch_bounds__(512) gather1(
        const u16* __restrict__ y1h, const u16* s1h, u16* h1h,   // s1h/h1h alias!
        const int* __restrict__ cnt, const int* __restrict__ ell) {
    int w    = threadIdx.x >> 6;
    int lane = threadIdx.x & 63;
    int node = blockIdx.x * 8 + w;   // grid = NN/8

    int dg  = cnt[node];
    int dgc = dg < CAP ? dg : CAP;
    int ids = (lane < dgc) ? ell[(size_t)node * CAP + lane] : 0;
    int grp = lane >> 4, fl = lane & 15;

    float a0 = 0, a1 = 0, a2 = 0, a3 = 0;
    float c0 = 0, c1 = 0, c2 = 0, c3 = 0;
    int j = 0;
    for (; j + 8 <= dgc; j += 8) {
        int s0 = __shfl(ids, j + grp);
        int s1 = __shfl(ids, j + 4 + grp);
        ushort4 u0 = ((const ushort4*)(y1h + (size_t)s0 * 64))[fl];
        ushort4 u1 = ((const ushort4*)(y1h + (size_t)s1 * 64))[fl];
        a0 += b2f(u0.x); a1 += b2f(u0.y); a2 += b2f(u0.z); a3 += b2f(u0.w);
        c0 += b2f(u1.x); c1 += b2f(u1.y); c2 += b2f(u1.z); c3 += b2f(u1.w);
    }
    for (; j < dgc; j += 4) {
        int jj = j + grp;
        int s0 = __shfl(ids, jj);
        if (jj < dgc) {
            ushort4 u0 = ((const ushort4*)(y1h + (size_t)s0 * 64))[fl];
            a0 += b2f(u0.x); a1 += b2f(u0.y); a2 += b2f(u0.z); a3 += b2f(u0.w);
        }
    }
    a0 += c0; a1 += c1; a2 += c2; a3 += c3;
    a0 += __shfl_xor(a0, 16); a1 += __shfl_xor(a1, 16);
    a2 += __shfl_xor(a2, 16); a3 += __shfl_xor(a3, 16);
    a0 += __shfl_xor(a0, 32); a1 += __shfl_xor(a1, 32);
    a2 += __shfl_xor(a2, 32); a3 += __shfl_xor(a3, 32);

    float inv = 1.0f / (float)(dg > 1 ? dg : 1);
    // own s1 row (read before the in-place store below; same-wave ordering)
    ushort4 sv = ((const ushort4*)(s1h + (size_t)node * 64))[fl];
    ushort4 out;
    out.x = f2b(fmaxf(a0 * inv + b2f(sv.x), 0.0f));
    out.y = f2b(fmaxf(a1 * inv + b2f(sv.y), 0.0f));
    out.z = f2b(fmaxf(a2 * inv + b2f(sv.z), 0.0f));
    out.w = f2b(fmaxf(a3 * inv + b2f(sv.w), 0.0f));
    if (lane < 16) ((ushort4*)(h1h + (size_t)node * 64))[fl] = out;
}

// ---------------- xform2: y2h = bf16(h1@w2l), s2h = bf16(h1@w2r + b2) ----------------
__global__ void __launch_bounds__(512) xform2(
        const u16* __restrict__ h1h,
        const float* __restrict__ w2l, const float* __restrict__ b2v,
        const float* __restrict__ w2r,
        u16* __restrict__ y2h, u16* __restrict__ s2h) {
    __shared__ float lw2l[64 * 32];
    __shared__ float lw2r[64 * 32];
    __shared__ float lb2[32];
    for (int i = threadIdx.x; i < 64 * 32; i += 512) { lw2l[i] = w2l[i]; lw2r[i] = w2r[i]; }
    if (threadIdx.x < 32) lb2[threadIdx.x] = b2v[threadIdx.x];
    __syncthreads();

    int w    = threadIdx.x >> 6;
    int lane = threadIdx.x & 63;
    int n0   = (blockIdx.x * 8 + w) * 8;
    if (n0 >= NN) return;

    float hr[8];
#pragma unroll
    for (int r = 0; r < 8; ++r) hr[r] = b2f(h1h[(size_t)(n0 + r) * 64 + lane]);

    int col = lane & 31;
    int sel = lane >> 5;                 // 0: y2 (no bias), 1: s2 (+b2)
    const float* W = sel ? lw2r : lw2l;
    float acc[8];
    float bias = sel ? lb2[col] : 0.0f;
#pragma unroll
    for (int r = 0; r < 8; ++r) acc[r] = bias;

#pragma unroll
    for (int k = 0; k < 64; ++k) {
        float wv = W[k * 32 + col];
#pragma unroll
        for (int r = 0; r < 8; ++r) {
            float xv = __shfl(hr[r], k);
            acc[r] += xv * wv;
        }
    }

#pragma unroll
    for (int r = 0; r < 8; ++r) {
        u16 v = f2b(acc[r]);
        if (sel == 0) y2h[(size_t)(n0 + r) * 32 + col] = v;
        else          s2h[(size_t)(n0 + r) * 32 + col] = v;
    }
}

// ---------------- gather2: h2 = relu(mean(y2h) + s2h); z = h2@wp+bp; logits ----------
__global__ void __launch_bounds__(512) gather2(
        const u16* __restrict__ y2h, const u16* __restrict__ s2h,
        const int* __restrict__ cnt, const int* __restrict__ ell,
        const float* __restrict__ wp, const float* __restrict__ bp,
        const float* __restrict__ wc, const float* __restrict__ bc,
        float* __restrict__ logits, float* __restrict__ zout) {
    __shared__ float lwp[32 * 32];
    __shared__ float lwc[64];
    __shared__ float lbp[32], lbc[2];
    __shared__ float sm2[8][32];
    __shared__ float sh2[8][32];
    __shared__ float sz[8][32];

    for (int i = threadIdx.x; i < 32 * 32; i += 512) lwp[i] = wp[i];
    if (threadIdx.x < 64) lwc[threadIdx.x] = wc[threadIdx.x];
    if (threadIdx.x < 32) lbp[threadIdx.x] = bp[threadIdx.x];
    if (threadIdx.x < 2) lbc[threadIdx.x] = bc[threadIdx.x];

    int w    = threadIdx.x >> 6;
    int lane = threadIdx.x & 63;
    int node = blockIdx.x * 8 + w;

    int dg  = cnt[node];
    int dgc = dg < CAP ? dg : CAP;
    int ids = (lane < dgc) ? ell[(size_t)node * CAP + lane] : 0;
    int grp = lane >> 3, fl = lane & 7;

    float a0 = 0, a1 = 0, a2 = 0, a3 = 0;
    float c0 = 0, c1 = 0, c2 = 0, c3 = 0;
    int j = 0;
    for (; j + 16 <= dgc; j += 16) {
        int s0 = __shfl(ids, j + grp);
        int s1 = __shfl(ids, j + 8 + grp);
        ushort4 u0 = ((const ushort4*)(y2h + (size_t)s0 * 32))[fl];
        ushort4 u1 = ((const ushort4*)(y2h + (size_t)s1 * 32))[fl];
        a0 += b2f(u0.x); a1 += b2f(u0.y); a2 += b2f(u0.z); a3 += b2f(u0.w);
        c0 += b2f(u1.x); c1 += b2f(u1.y); c2 += b2f(u1.z); c3 += b2f(u1.w);
    }
    for (; j < dgc; j += 8) {
        int jj = j + grp;
        int s0 = __shfl(ids, jj);
        if (jj < dgc) {
            ushort4 u0 = ((const ushort4*)(y2h + (size_t)s0 * 32))[fl];
            a0 += b2f(u0.x); a1 += b2f(u0.y); a2 += b2f(u0.z); a3 += b2f(u0.w);
        }
    }
    a0 += c0; a1 += c1; a2 += c2; a3 += c3;
    a0 += __shfl_xor(a0, 8);  a1 += __shfl_xor(a1, 8);
    a2 += __shfl_xor(a2, 8);  a3 += __shfl_xor(a3, 8);
    a0 += __shfl_xor(a0, 16); a1 += __shfl_xor(a1, 16);
    a2 += __shfl_xor(a2, 16); a3 += __shfl_xor(a3, 16);
    a0 += __shfl_xor(a0, 32); a1 += __shfl_xor(a1, 32);
    a2 += __shfl_xor(a2, 32); a3 += __shfl_xor(a3, 32);

    float inv = 1.0f / (float)(dg > 1 ? dg : 1);
    if (lane < 8) {
        float4 m4 = make_float4(a0 * inv, a1 * inv, a2 * inv, a3 * inv);
        ((float4*)sm2[w])[fl] = m4;
    }
    __syncthreads();

    // h2 = relu(mean + s2)   [32]   (s2 already includes b2)
    if (lane < 32) {
        float h2 = fmaxf(sm2[w][lane] + b2f(s2h[(size_t)node * 32 + lane]), 0.0f);
        sh2[w][lane] = h2;
    }
    __syncthreads();

    // z = h2 @ wp + bp   [32]
    if (lane < 32) {
        float z = lbp[lane];
#pragma unroll
        for (int k = 0; k < 32; ++k) {
            z += sh2[w][k] * lwp[k * 32 + lane];
        }
        zout[(size_t)node * 32 + lane] = z;
        sz[w][lane] = z;
    }
    __syncthreads();

    // logits = z @ wc + bc   [2]
    if (lane < 2) {
        float lg = lbc[lane];
#pragma unroll
        for (int k = 0; k < 32; ++k) {
            lg += sz[w][k] * lwc[k * 2 + lane];
        }
        logits[(size_t)node * 2 + lane] = lg;
    }
}

extern "C" void kernel_launch(void* const* d_in, const int* in_sizes, int n_in,
                              void* d_out, int out_size, void* d_ws, size_t ws_size,
                              hipStream_t stream) {
    const float* x    = (const float*)d_in[0];
    const int*   ei   = (const int*)d_in[1];
    const float* w1l  = (const float*)d_in[2];
    const float* b1   = (const float*)d_in[3];
    const float* w1r  = (const float*)d_in[4];
    const float* w2l  = (const float*)d_in[5];
    const float* b2   = (const float*)d_in[6];
    const float* w2r  = (const float*)d_in[7];
    const float* wp   = (const float*)d_in[8];
    const float* bp   = (const float*)d_in[9];
    const float* wc   = (const float*)d_in[10];
    const float* bc   = (const float*)d_in[11];

    const int* src = ei;            // edge_index[0]
    const int* dst = ei + NE;       // edge_index[1]

    // workspace layout (51.6 MB total):
    //   cnt  int [NN]                       0.4 MB @ 0
    //   ell  int [NN*CAP]                  25.6 MB @ 400000
    //   y1h  u16 [NN*64]                   12.8 MB @ 26000000   (dead after gather1)
    //     -> reused by y2h u16 [NN*32] (6.4) + s2h u16 [NN*32] (6.4)
    //   s1h  u16 [NN*64]                   12.8 MB @ 38800000   (h1h written in-place)
    char* base = (char*)d_ws;
    int* cnt = (int*)base;
    int* ell = (int*)(base + 400000);
    u16* y1h = (u16*)(base + 26000000);
    u16* s1h = (u16*)(base + 38800000);
    u16* h1h = s1h;                          // in-place: own-row read precedes store
    u16* y2h = y1h;                          // alias: y1h dead after gather1
    u16* s2h = y1h + (size_t)NN * 32;

    float* out_logits = (float*)d_out;                  // [NN*2]
    float* out_z      = (float*)d_out + (size_t)NN * 2; // [NN*32]

    hipMemsetAsync(cnt, 0, (size_t)NN * sizeof(int), stream);

    build_ell<<<(NE / 4 + 255) / 256, 256, 0, stream>>>(src, dst, cnt, ell);

    xform1<<<(NN + 63) / 64, 512, 0, stream>>>(x, w1l, b1, w1r, y1h, s1h);

    gather1<<<NN / 8, 512, 0, stream>>>(y1h, s1h, h1h, cnt, ell);

    xform2<<<(NN + 63) / 64, 512, 0, stream>>>(h1h, w2l, b2, w2r, y2h, s2h);

    gather2<<<NN / 8, 512, 0, stream>>>(y2h, s2h, cnt, ell, wp, bp, wc, bc,
                                        out_logits, out_z);
}

// Round 6
// 369.078 us; speedup vs baseline: 1.0361x; 1.0361x over previous
//
#include <hip/hip_runtime.h>

#define NN 100000
#define NE 1250000
#define CAP 64   // ELL capacity; deg ~ Poisson(12.5), P(deg>64) ~ 0

#define GB 2442  // build_ell blocks: ceil(NE/512)
#define GX 1563  // xform1 blocks:    ceil(NN/64)

typedef unsigned short u16;

__device__ inline float b2f(u16 h) { return __uint_as_float(((unsigned int)h) << 16); }
__device__ inline u16 f2b(float f) {
    unsigned int u = __float_as_uint(f);
    u = (u + 0x7FFFu + ((u >> 16) & 1u)) >> 16;   // RNE
    return (u16)u;
}

// ---------------- K1: build_ell (blocks 0..GB-1)  ∪  xform1 (blocks GB..GB+GX-1) ----
// build_ell: 1 thread/edge, scalar atomic slot + scatter store (latency-bound).
// xform1:    y1h = bf16(x@w1l), s1h = bf16(x@w1r + b1)  (VALU-bound).
// Independent work; role-split by blockIdx so both kinds co-reside per CU.
__global__ void __launch_bounds__(512) k1_ell_xform1(
        const int* __restrict__ src, const int* __restrict__ dst,
        int* __restrict__ cnt, int* __restrict__ ell,
        const float* __restrict__ x,
        const float* __restrict__ w1l, const float* __restrict__ b1,
        const float* __restrict__ w1r,
        u16* __restrict__ y1h, u16* __restrict__ s1h) {
    __shared__ float lwl[64 * 64];
    __shared__ float lwr[64 * 64];
    __shared__ float lb[64];

    if (blockIdx.x < GB) {
        int e = blockIdx.x * 512 + threadIdx.x;
        if (e < NE) {
            int s = src[e];
            int d = dst[e];
            int slot = atomicAdd(&cnt[d], 1);
            if (slot < CAP) ell[(size_t)d * CAP + slot] = s;
        }
        return;
    }

    // ---- xform1 role ----
    for (int i = threadIdx.x; i < 64 * 64; i += 512) { lwl[i] = w1l[i]; lwr[i] = w1r[i]; }
    if (threadIdx.x < 64) lb[threadIdx.x] = b1[threadIdx.x];
    __syncthreads();

    int w    = threadIdx.x >> 6;
    int lane = threadIdx.x & 63;
    int n0   = ((int)(blockIdx.x - GB) * 8 + w) * 8;   // 8 nodes per wave
    if (n0 >= NN) return;

    float xr[8];
#pragma unroll
    for (int r = 0; r < 8; ++r) xr[r] = x[(size_t)(n0 + r) * 64 + lane];

    float accy[8], accs[8];
    float bias = lb[lane];
#pragma unroll
    for (int r = 0; r < 8; ++r) { accy[r] = 0.0f; accs[r] = bias; }

#pragma unroll
    for (int k = 0; k < 64; ++k) {
        float wl = lwl[k * 64 + lane];
        float wr = lwr[k * 64 + lane];
#pragma unroll
        for (int r = 0; r < 8; ++r) {
            float xv = __shfl(xr[r], k);
            accy[r] += xv * wl;
            accs[r] += xv * wr;
        }
    }

#pragma unroll
    for (int r = 0; r < 8; ++r) {
        y1h[(size_t)(n0 + r) * 64 + lane] = f2b(accy[r]);
        s1h[(size_t)(n0 + r) * 64 + lane] = f2b(accs[r]);
    }
}

// ---------------- K2: gather1 + xform2 fused ----------------
// Per wave (1 node): mean over neighbors' y1h rows, h1 = relu(mean + s1) held
// in-register (all lanes hold full row as quads), then y2|s2 = h1@w2{l,r} via
// shfl broadcasts. y2 (cols 0..31) and s2 (cols 32..63) overwrite the node's
// own s1h row (read-before-write within the same wave).
__global__ void __launch_bounds__(512) k2_gather1_xform2(
        const u16* __restrict__ y1h, u16* s1h,            // s1h: in s1, out y2|s2
        const int* __restrict__ cnt, const int* __restrict__ ell,
        const float* __restrict__ w2l, const float* __restrict__ b2v,
        const float* __restrict__ w2r) {
    __shared__ float lw[2][64 * 32];   // [0]=w2l, [1]=w2r
    __shared__ float lb2[32];
    for (int i = threadIdx.x; i < 64 * 32; i += 512) { lw[0][i] = w2l[i]; lw[1][i] = w2r[i]; }
    if (threadIdx.x < 32) lb2[threadIdx.x] = b2v[threadIdx.x];
    __syncthreads();

    int w    = threadIdx.x >> 6;
    int lane = threadIdx.x & 63;
    int node = blockIdx.x * 8 + w;   // grid = NN/8

    int dg  = cnt[node];
    int dgc = dg < CAP ? dg : CAP;
    int ids = (lane < dgc) ? ell[(size_t)node * CAP + lane] : 0;
    int grp = lane >> 4, fl = lane & 15;

    float a0 = 0, a1 = 0, a2 = 0, a3 = 0;
    float c0 = 0, c1 = 0, c2 = 0, c3 = 0;
    int j = 0;
    for (; j + 8 <= dgc; j += 8) {
        int s0 = __shfl(ids, j + grp);
        int s1 = __shfl(ids, j + 4 + grp);
        ushort4 u0 = ((const ushort4*)(y1h + (size_t)s0 * 64))[fl];
        ushort4 u1 = ((const ushort4*)(y1h + (size_t)s1 * 64))[fl];
        a0 += b2f(u0.x); a1 += b2f(u0.y); a2 += b2f(u0.z); a3 += b2f(u0.w);
        c0 += b2f(u1.x); c1 += b2f(u1.y); c2 += b2f(u1.z); c3 += b2f(u1.w);
    }
    for (; j < dgc; j += 4) {
        int jj = j + grp;
        int s0 = __shfl(ids, jj);
        if (jj < dgc) {
            ushort4 u0 = ((const ushort4*)(y1h + (size_t)s0 * 64))[fl];
            a0 += b2f(u0.x); a1 += b2f(u0.y); a2 += b2f(u0.z); a3 += b2f(u0.w);
        }
    }
    a0 += c0; a1 += c1; a2 += c2; a3 += c3;
    a0 += __shfl_xor(a0, 16); a1 += __shfl_xor(a1, 16);
    a2 += __shfl_xor(a2, 16); a3 += __shfl_xor(a3, 16);
    a0 += __shfl_xor(a0, 32); a1 += __shfl_xor(a1, 32);
    a2 += __shfl_xor(a2, 32); a3 += __shfl_xor(a3, 32);

    float inv = 1.0f / (float)(dg > 1 ? dg : 1);
    // own s1 row quad (every lane loads quad fl = lane&15; redundant across groups)
    ushort4 sv = ((const ushort4*)(s1h + (size_t)node * 64))[fl];
    float h0 = fmaxf(a0 * inv + b2f(sv.x), 0.0f);
    float h1 = fmaxf(a1 * inv + b2f(sv.y), 0.0f);
    float h2 = fmaxf(a2 * inv + b2f(sv.z), 0.0f);
    float h3 = fmaxf(a3 * inv + b2f(sv.w), 0.0f);

    // xform2: lane = (sel, col); y2 = h1@w2l, s2 = h1@w2r + b2
    int col = lane & 31;
    int sel = lane >> 5;
    const float* W = lw[sel];
    float acc = sel ? lb2[col] : 0.0f;
#pragma unroll
    for (int k = 0; k < 64; ++k) {
        float hv;
        if ((k & 3) == 0)      hv = __shfl(h0, k >> 2);
        else if ((k & 3) == 1) hv = __shfl(h1, k >> 2);
        else if ((k & 3) == 2) hv = __shfl(h2, k >> 2);
        else                   hv = __shfl(h3, k >> 2);
        acc += hv * W[k * 32 + col];
    }
    // overwrite own s1 row: y2 at [0..31], s2 at [32..63]
    s1h[(size_t)node * 64 + sel * 32 + col] = f2b(acc);
}

// ---------------- K3: gather2 epilogue ----------------
// ys row (stride 64 u16): y2 at +0..31, s2 at +32..63.
// h2 = relu(mean(y2) + s2); z = h2@wp+bp; logits = z@wc+bc.
__global__ void __launch_bounds__(512) k3_gather2(
        const u16* __restrict__ ys,
        const int* __restrict__ cnt, const int* __restrict__ ell,
        const float* __restrict__ wp, const float* __restrict__ bp,
        const float* __restrict__ wc, const float* __restrict__ bc,
        float* __restrict__ logits, float* __restrict__ zout) {
    __shared__ float lwp[32 * 32];
    __shared__ float lwc[64];
    __shared__ float lbp[32], lbc[2];
    __shared__ float sm2[8][32];
    __shared__ float sh2[8][32];
    __shared__ float sz[8][32];

    for (int i = threadIdx.x; i < 32 * 32; i += 512) lwp[i] = wp[i];
    if (threadIdx.x < 64) lwc[threadIdx.x] = wc[threadIdx.x];
    if (threadIdx.x < 32) lbp[threadIdx.x] = bp[threadIdx.x];
    if (threadIdx.x < 2) lbc[threadIdx.x] = bc[threadIdx.x];

    int w    = threadIdx.x >> 6;
    int lane = threadIdx.x & 63;
    int node = blockIdx.x * 8 + w;

    int dg  = cnt[node];
    int dgc = dg < CAP ? dg : CAP;
    int ids = (lane < dgc) ? ell[(size_t)node * CAP + lane] : 0;
    int grp = lane >> 3, fl = lane & 7;

    float a0 = 0, a1 = 0, a2 = 0, a3 = 0;
    float c0 = 0, c1 = 0, c2 = 0, c3 = 0;
    int j = 0;
    for (; j + 16 <= dgc; j += 16) {
        int s0 = __shfl(ids, j + grp);
        int s1 = __shfl(ids, j + 8 + grp);
        ushort4 u0 = ((const ushort4*)(ys + (size_t)s0 * 64))[fl];
        ushort4 u1 = ((const ushort4*)(ys + (size_t)s1 * 64))[fl];
        a0 += b2f(u0.x); a1 += b2f(u0.y); a2 += b2f(u0.z); a3 += b2f(u0.w);
        c0 += b2f(u1.x); c1 += b2f(u1.y); c2 += b2f(u1.z); c3 += b2f(u1.w);
    }
    for (; j < dgc; j += 8) {
        int jj = j + grp;
        int s0 = __shfl(ids, jj);
        if (jj < dgc) {
            ushort4 u0 = ((const ushort4*)(ys + (size_t)s0 * 64))[fl];
            a0 += b2f(u0.x); a1 += b2f(u0.y); a2 += b2f(u0.z); a3 += b2f(u0.w);
        }
    }
    a0 += c0; a1 += c1; a2 += c2; a3 += c3;
    a0 += __shfl_xor(a0, 8);  a1 += __shfl_xor(a1, 8);
    a2 += __shfl_xor(a2, 8);  a3 += __shfl_xor(a3, 8);
    a0 += __shfl_xor(a0, 16); a1 += __shfl_xor(a1, 16);
    a2 += __shfl_xor(a2, 16); a3 += __shfl_xor(a3, 16);
    a0 += __shfl_xor(a0, 32); a1 += __shfl_xor(a1, 32);
    a2 += __shfl_xor(a2, 32); a3 += __shfl_xor(a3, 32);

    float inv = 1.0f / (float)(dg > 1 ? dg : 1);
    if (lane < 8) {
        float4 m4 = make_float4(a0 * inv, a1 * inv, a2 * inv, a3 * inv);
        ((float4*)sm2[w])[fl] = m4;
    }
    __syncthreads();

    // h2 = relu(mean + s2)   (s2 already includes b2)
    if (lane < 32) {
        float h2 = fmaxf(sm2[w][lane] + b2f(ys[(size_t)node * 64 + 32 + lane]), 0.0f);
        sh2[w][lane] = h2;
    }
    __syncthreads();

    // z = h2 @ wp + bp
    if (lane < 32) {
        float z = lbp[lane];
#pragma unroll
        for (int k = 0; k < 32; ++k) {
            z += sh2[w][k] * lwp[k * 32 + lane];
        }
        zout[(size_t)node * 32 + lane] = z;
        sz[w][lane] = z;
    }
    __syncthreads();

    // logits = z @ wc + bc
    if (lane < 2) {
        float lg = lbc[lane];
#pragma unroll
        for (int k = 0; k < 32; ++k) {
            lg += sz[w][k] * lwc[k * 2 + lane];
        }
        logits[(size_t)node * 2 + lane] = lg;
    }
}

extern "C" void kernel_launch(void* const* d_in, const int* in_sizes, int n_in,
                              void* d_out, int out_size, void* d_ws, size_t ws_size,
                              hipStream_t stream) {
    const float* x    = (const float*)d_in[0];
    const int*   ei   = (const int*)d_in[1];
    const float* w1l  = (const float*)d_in[2];
    const float* b1   = (const float*)d_in[3];
    const float* w1r  = (const float*)d_in[4];
    const float* w2l  = (const float*)d_in[5];
    const float* b2   = (const float*)d_in[6];
    const float* w2r  = (const float*)d_in[7];
    const float* wp   = (const float*)d_in[8];
    const float* bp   = (const float*)d_in[9];
    const float* wc   = (const float*)d_in[10];
    const float* bc   = (const float*)d_in[11];

    const int* src = ei;            // edge_index[0]
    const int* dst = ei + NE;       // edge_index[1]

    // workspace layout (51.6 MB total):
    //   cnt  int [NN]              0.4 MB @ 0
    //   ell  int [NN*CAP]         25.6 MB @ 400000
    //   y1h  u16 [NN*64]          12.8 MB @ 26000000   (dead after K2)
    //   s1h  u16 [NN*64]          12.8 MB @ 38800000   (K2 rewrites rows in place
    //                                                   as y2 [0..31] | s2 [32..63])
    char* base = (char*)d_ws;
    int* cnt = (int*)base;
    int* ell = (int*)(base + 400000);
    u16* y1h = (u16*)(base + 26000000);
    u16* s1h = (u16*)(base + 38800000);

    float* out_logits = (float*)d_out;                  // [NN*2]
    float* out_z      = (float*)d_out + (size_t)NN * 2; // [NN*32]

    hipMemsetAsync(cnt, 0, (size_t)NN * sizeof(int), stream);

    k1_ell_xform1<<<GB + GX, 512, 0, stream>>>(src, dst, cnt, ell,
                                               x, w1l, b1, w1r, y1h, s1h);

    k2_gather1_xform2<<<NN / 8, 512, 0, stream>>>(y1h, s1h, cnt, ell, w2l, b2, w2r);

    k3_gather2<<<NN / 8, 512, 0, stream>>>(s1h, cnt, ell, wp, bp, wc, bc,
                                           out_logits, out_z);
}

// Round 7
// 366.645 us; speedup vs baseline: 1.0430x; 1.0066x over previous
//
#include <hip/hip_runtime.h>

#define NN 100000
#define NE 1250000
#define CAP 64   // ELL capacity; deg ~ Poisson(12.5), P(deg>64) ~ 0

typedef unsigned short u16;

__device__ inline float b2f(u16 h) { return __uint_as_float(((unsigned int)h) << 16); }
__device__ inline u16 f2b(float f) {
    unsigned int u = __float_as_uint(f);
    u = (u + 0x7FFFu + ((u >> 16) & 1u)) >> 16;   // RNE
    return (u16)u;
}

// ---------------- build_ell: 1 thread/edge, scalar atomic + scatter store ----------
// Latency-bound: zero LDS, max occupancy, one independent atomic chain per thread.
__global__ void build_ell(const int* __restrict__ src, const int* __restrict__ dst,
                          int* __restrict__ cnt, int* __restrict__ ell) {
    int e = blockIdx.x * blockDim.x + threadIdx.x;
    if (e >= NE) return;
    int s = src[e];
    int d = dst[e];
    int slot = atomicAdd(&cnt[d], 1);
    if (slot < CAP) ell[(size_t)d * CAP + slot] = s;
}

// ---------------- xform1: y1h = bf16(x@w1l), s1h = bf16(x@w1r + b1) ----------------
// wave = 8 nodes; x rows in registers; per-k: 2 LDS weight reads + 8 shfl + 16 FMA
__global__ void __launch_bounds__(512) xform1(
        const float* __restrict__ x,
        const float* __restrict__ w1l, const float* __restrict__ b1,
        const float* __restrict__ w1r,
        u16* __restrict__ y1h, u16* __restrict__ s1h) {
    __shared__ float lwl[64 * 64];
    __shared__ float lwr[64 * 64];
    __shared__ float lb[64];
    for (int i = threadIdx.x; i < 64 * 64; i += 512) { lwl[i] = w1l[i]; lwr[i] = w1r[i]; }
    if (threadIdx.x < 64) lb[threadIdx.x] = b1[threadIdx.x];
    __syncthreads();

    int w    = threadIdx.x >> 6;
    int lane = threadIdx.x & 63;
    int n0   = (blockIdx.x * 8 + w) * 8;   // 8 nodes per wave
    if (n0 >= NN) return;

    float xr[8];
#pragma unroll
    for (int r = 0; r < 8; ++r) xr[r] = x[(size_t)(n0 + r) * 64 + lane];

    float accy[8], accs[8];
    float bias = lb[lane];
#pragma unroll
    for (int r = 0; r < 8; ++r) { accy[r] = 0.0f; accs[r] = bias; }

#pragma unroll
    for (int k = 0; k < 64; ++k) {
        float wl = lwl[k * 64 + lane];
        float wr = lwr[k * 64 + lane];
#pragma unroll
        for (int r = 0; r < 8; ++r) {
            float xv = __shfl(xr[r], k);
            accy[r] += xv * wl;
            accs[r] += xv * wr;
        }
    }

#pragma unroll
    for (int r = 0; r < 8; ++r) {
        y1h[(size_t)(n0 + r) * 64 + lane] = f2b(accy[r]);
        s1h[(size_t)(n0 + r) * 64 + lane] = f2b(accs[r]);
    }
}

// ---------------- K2: gather1 + xform2 fused ----------------
// Per wave (1 node): mean over neighbors' y1h rows, h1 = relu(mean + s1) held
// in-register (all lanes hold full row as quads), then y2|s2 = h1@w2{l,r} via
// shfl broadcasts. y2 (cols 0..31) and s2 (cols 32..63) overwrite the node's
// own s1h row (read-before-write within the same wave).
__global__ void __launch_bounds__(512) k2_gather1_xform2(
        const u16* __restrict__ y1h, u16* s1h,            // s1h: in s1, out y2|s2
        const int* __restrict__ cnt, const int* __restrict__ ell,
        const float* __restrict__ w2l, const float* __restrict__ b2v,
        const float* __restrict__ w2r) {
    __shared__ float lw[2][64 * 32];   // [0]=w2l, [1]=w2r
    __shared__ float lb2[32];
    for (int i = threadIdx.x; i < 64 * 32; i += 512) { lw[0][i] = w2l[i]; lw[1][i] = w2r[i]; }
    if (threadIdx.x < 32) lb2[threadIdx.x] = b2v[threadIdx.x];
    __syncthreads();

    int w    = threadIdx.x >> 6;
    int lane = threadIdx.x & 63;
    int node = blockIdx.x * 8 + w;   // grid = NN/8

    int dg  = cnt[node];
    int dgc = dg < CAP ? dg : CAP;
    int ids = (lane < dgc) ? ell[(size_t)node * CAP + lane] : 0;
    int grp = lane >> 4, fl = lane & 15;

    float a0 = 0, a1 = 0, a2 = 0, a3 = 0;
    float c0 = 0, c1 = 0, c2 = 0, c3 = 0;
    int j = 0;
    for (; j + 8 <= dgc; j += 8) {
        int s0 = __shfl(ids, j + grp);
        int s1 = __shfl(ids, j + 4 + grp);
        ushort4 u0 = ((const ushort4*)(y1h + (size_t)s0 * 64))[fl];
        ushort4 u1 = ((const ushort4*)(y1h + (size_t)s1 * 64))[fl];
        a0 += b2f(u0.x); a1 += b2f(u0.y); a2 += b2f(u0.z); a3 += b2f(u0.w);
        c0 += b2f(u1.x); c1 += b2f(u1.y); c2 += b2f(u1.z); c3 += b2f(u1.w);
    }
    for (; j < dgc; j += 4) {
        int jj = j + grp;
        int s0 = __shfl(ids, jj);
        if (jj < dgc) {
            ushort4 u0 = ((const ushort4*)(y1h + (size_t)s0 * 64))[fl];
            a0 += b2f(u0.x); a1 += b2f(u0.y); a2 += b2f(u0.z); a3 += b2f(u0.w);
        }
    }
    a0 += c0; a1 += c1; a2 += c2; a3 += c3;
    a0 += __shfl_xor(a0, 16); a1 += __shfl_xor(a1, 16);
    a2 += __shfl_xor(a2, 16); a3 += __shfl_xor(a3, 16);
    a0 += __shfl_xor(a0, 32); a1 += __shfl_xor(a1, 32);
    a2 += __shfl_xor(a2, 32); a3 += __shfl_xor(a3, 32);

    float inv = 1.0f / (float)(dg > 1 ? dg : 1);
    // own s1 row quad (every lane loads quad fl = lane&15; redundant across groups)
    ushort4 sv = ((const ushort4*)(s1h + (size_t)node * 64))[fl];
    float h0 = fmaxf(a0 * inv + b2f(sv.x), 0.0f);
    float h1 = fmaxf(a1 * inv + b2f(sv.y), 0.0f);
    float h2 = fmaxf(a2 * inv + b2f(sv.z), 0.0f);
    float h3 = fmaxf(a3 * inv + b2f(sv.w), 0.0f);

    // xform2: lane = (sel, col); y2 = h1@w2l, s2 = h1@w2r + b2
    int col = lane & 31;
    int sel = lane >> 5;
    const float* W = lw[sel];
    float acc = sel ? lb2[col] : 0.0f;
#pragma unroll
    for (int k = 0; k < 64; ++k) {
        float hv;
        if ((k & 3) == 0)      hv = __shfl(h0, k >> 2);
        else if ((k & 3) == 1) hv = __shfl(h1, k >> 2);
        else if ((k & 3) == 2) hv = __shfl(h2, k >> 2);
        else                   hv = __shfl(h3, k >> 2);
        acc += hv * W[k * 32 + col];
    }
    // overwrite own s1 row: y2 at [0..31], s2 at [32..63]
    s1h[(size_t)node * 64 + sel * 32 + col] = f2b(acc);
}

// ---------------- K3: gather2 epilogue ----------------
// ys row (stride 64 u16): y2 at +0..31, s2 at +32..63.
// h2 = relu(mean(y2) + s2); z = h2@wp+bp; logits = z@wc+bc.
__global__ void __launch_bounds__(512) k3_gather2(
        const u16* __restrict__ ys,
        const int* __restrict__ cnt, const int* __restrict__ ell,
        const float* __restrict__ wp, const float* __restrict__ bp,
        const float* __restrict__ wc, const float* __restrict__ bc,
        float* __restrict__ logits, float* __restrict__ zout) {
    __shared__ float lwp[32 * 32];
    __shared__ float lwc[64];
    __shared__ float lbp[32], lbc[2];
    __shared__ float sm2[8][32];
    __shared__ float sh2[8][32];
    __shared__ float sz[8][32];

    for (int i = threadIdx.x; i < 32 * 32; i += 512) lwp[i] = wp[i];
    if (threadIdx.x < 64) lwc[threadIdx.x] = wc[threadIdx.x];
    if (threadIdx.x < 32) lbp[threadIdx.x] = bp[threadIdx.x];
    if (threadIdx.x < 2) lbc[threadIdx.x] = bc[threadIdx.x];

    int w    = threadIdx.x >> 6;
    int lane = threadIdx.x & 63;
    int node = blockIdx.x * 8 + w;

    int dg  = cnt[node];
    int dgc = dg < CAP ? dg : CAP;
    int ids = (lane < dgc) ? ell[(size_t)node * CAP + lane] : 0;
    int grp = lane >> 3, fl = lane & 7;

    float a0 = 0, a1 = 0, a2 = 0, a3 = 0;
    float c0 = 0, c1 = 0, c2 = 0, c3 = 0;
    int j = 0;
    for (; j + 16 <= dgc; j += 16) {
        int s0 = __shfl(ids, j + grp);
        int s1 = __shfl(ids, j + 8 + grp);
        ushort4 u0 = ((const ushort4*)(ys + (size_t)s0 * 64))[fl];
        ushort4 u1 = ((const ushort4*)(ys + (size_t)s1 * 64))[fl];
        a0 += b2f(u0.x); a1 += b2f(u0.y); a2 += b2f(u0.z); a3 += b2f(u0.w);
        c0 += b2f(u1.x); c1 += b2f(u1.y); c2 += b2f(u1.z); c3 += b2f(u1.w);
    }
    for (; j < dgc; j += 8) {
        int jj = j + grp;
        int s0 = __shfl(ids, jj);
        if (jj < dgc) {
            ushort4 u0 = ((const ushort4*)(ys + (size_t)s0 * 64))[fl];
            a0 += b2f(u0.x); a1 += b2f(u0.y); a2 += b2f(u0.z); a3 += b2f(u0.w);
        }
    }
    a0 += c0; a1 += c1; a2 += c2; a3 += c3;
    a0 += __shfl_xor(a0, 8);  a1 += __shfl_xor(a1, 8);
    a2 += __shfl_xor(a2, 8);  a3 += __shfl_xor(a3, 8);
    a0 += __shfl_xor(a0, 16); a1 += __shfl_xor(a1, 16);
    a2 += __shfl_xor(a2, 16); a3 += __shfl_xor(a3, 16);
    a0 += __shfl_xor(a0, 32); a1 += __shfl_xor(a1, 32);
    a2 += __shfl_xor(a2, 32); a3 += __shfl_xor(a3, 32);

    float inv = 1.0f / (float)(dg > 1 ? dg : 1);
    if (lane < 8) {
        float4 m4 = make_float4(a0 * inv, a1 * inv, a2 * inv, a3 * inv);
        ((float4*)sm2[w])[fl] = m4;
    }
    __syncthreads();

    // h2 = relu(mean + s2)   (s2 already includes b2)
    if (lane < 32) {
        float h2 = fmaxf(sm2[w][lane] + b2f(ys[(size_t)node * 64 + 32 + lane]), 0.0f);
        sh2[w][lane] = h2;
    }
    __syncthreads();

    // z = h2 @ wp + bp
    if (lane < 32) {
        float z = lbp[lane];
#pragma unroll
        for (int k = 0; k < 32; ++k) {
            z += sh2[w][k] * lwp[k * 32 + lane];
        }
        zout[(size_t)node * 32 + lane] = z;
        sz[w][lane] = z;
    }
    __syncthreads();

    // logits = z @ wc + bc
    if (lane < 2) {
        float lg = lbc[lane];
#pragma unroll
        for (int k = 0; k < 32; ++k) {
            lg += sz[w][k] * lwc[k * 2 + lane];
        }
        logits[(size_t)node * 2 + lane] = lg;
    }
}

extern "C" void kernel_launch(void* const* d_in, const int* in_sizes, int n_in,
                              void* d_out, int out_size, void* d_ws, size_t ws_size,
                              hipStream_t stream) {
    const float* x    = (const float*)d_in[0];
    const int*   ei   = (const int*)d_in[1];
    const float* w1l  = (const float*)d_in[2];
    const float* b1   = (const float*)d_in[3];
    const float* w1r  = (const float*)d_in[4];
    const float* w2l  = (const float*)d_in[5];
    const float* b2   = (const float*)d_in[6];
    const float* w2r  = (const float*)d_in[7];
    const float* wp   = (const float*)d_in[8];
    const float* bp   = (const float*)d_in[9];
    const float* wc   = (const float*)d_in[10];
    const float* bc   = (const float*)d_in[11];

    const int* src = ei;            // edge_index[0]
    const int* dst = ei + NE;       // edge_index[1]

    // workspace layout (51.6 MB total):
    //   cnt  int [NN]              0.4 MB @ 0
    //   ell  int [NN*CAP]         25.6 MB @ 400000
    //   y1h  u16 [NN*64]          12.8 MB @ 26000000   (dead after K2)
    //   s1h  u16 [NN*64]          12.8 MB @ 38800000   (K2 rewrites rows in place
    //                                                   as y2 [0..31] | s2 [32..63])
    char* base = (char*)d_ws;
    int* cnt = (int*)base;
    int* ell = (int*)(base + 400000);
    u16* y1h = (u16*)(base + 26000000);
    u16* s1h = (u16*)(base + 38800000);

    float* out_logits = (float*)d_out;                  // [NN*2]
    float* out_z      = (float*)d_out + (size_t)NN * 2; // [NN*32]

    hipMemsetAsync(cnt, 0, (size_t)NN * sizeof(int), stream);

    build_ell<<<(NE + 255) / 256, 256, 0, stream>>>(src, dst, cnt, ell);

    xform1<<<(NN + 63) / 64, 512, 0, stream>>>(x, w1l, b1, w1r, y1h, s1h);

    k2_gather1_xform2<<<NN / 8, 512, 0, stream>>>(y1h, s1h, cnt, ell, w2l, b2, w2r);

    k3_gather2<<<NN / 8, 512, 0, stream>>>(s1h, cnt, ell, wp, bp, wc, bc,
                                           out_logits, out_z);
}